// Round 10
// baseline (86.251 us; speedup 1.0000x reference)
//
#include <hip/hip_runtime.h>
#include <hip/hip_fp16.h>

#define SS 2048
#define L2E 1.44269504088896340736f

typedef _Float16 f16x4 __attribute__((ext_vector_type(4)));
typedef _Float16 f16x8 __attribute__((ext_vector_type(8)));
typedef float f32x4 __attribute__((ext_vector_type(4)));

#define GLDS16(g, l) __builtin_amdgcn_global_load_lds(                          \
    (const __attribute__((address_space(1))) void*)(g),                         \
    (__attribute__((address_space(3))) void*)(l), 16, 0, 0)
#define GLDS4(g, l) __builtin_amdgcn_global_load_lds(                           \
    (const __attribute__((address_space(1))) void*)(g),                         \
    (__attribute__((address_space(3))) void*)(l), 4, 0, 0)

// ---------------- Kernel A: QKV projection ----------------
// Fragment layouts:
//  qf/kf: [b][tile=s/16][ (feat/8)*16 + s%16 ][8 f16]; q pre-scaled by log2e;
//         feat group 3 (feats 24..31) ZERO.
//  vf (vd-blocks interleaved per lane so PV reads are one b128):
//     per 16k chunk: f16idx = (((k>>2)&3)*16 + (vd&15))*8 + (vd>>4)*4 + (k&3)
__global__ __launch_bounds__(256) void qkv_kernel(
    const float* __restrict__ x, const float* __restrict__ Wq,
    const float* __restrict__ Wk, const float* __restrict__ Wv,
    _Float16* __restrict__ qfp, _Float16* __restrict__ kfp,
    _Float16* __restrict__ vfp)
{
    __shared__ float xsT[64 * 64];     // [f][row], 16 KB
    __shared__ float wc[64 * 96];      // [f][c]: q24|k24|v32|pad16, 24 KB

    int t = threadIdx.x;
    for (int i = t; i < 384; i += 256) {
        float4 v = ((const float4*)Wq)[i];
        int f = (i * 4) / 24, c = (i * 4) % 24;
        *(float4*)&wc[f * 96 + c] = v;
    }
    for (int i = t; i < 384; i += 256) {
        float4 v = ((const float4*)Wk)[i];
        int f = (i * 4) / 24, c = (i * 4) % 24;
        *(float4*)&wc[f * 96 + 24 + c] = v;
    }
    for (int i = t; i < 512; i += 256) {
        float4 v = ((const float4*)Wv)[i];
        int f = i >> 3, c = (i * 4) & 31;
        *(float4*)&wc[f * 96 + 48 + c] = v;
    }
    {
        int f = t >> 2, seg = t & 3;
        *(float4*)&wc[f * 96 + 80 + seg * 4] = (float4){0.f, 0.f, 0.f, 0.f};
    }
    long rowbase = (long)blockIdx.x * 64;
    const float4* xg = (const float4*)(x + rowbase * 64);
    for (int i = t; i < 1024; i += 256) {
        int r = i >> 4, c4 = i & 15;
        float4 v = xg[i];
        xsT[(c4 * 4 + 0) * 64 + r] = v.x;
        xsT[(c4 * 4 + 1) * 64 + r] = v.y;
        xsT[(c4 * 4 + 2) * 64 + r] = v.z;
        xsT[(c4 * 4 + 3) * 64 + r] = v.w;
    }
    __syncthreads();

    int rg = t >> 3;   // 32 row-groups of 2 rows
    int cg = t & 7;    // 8 col-groups of 12 cols
    float acc0[12], acc1[12];
    #pragma unroll
    for (int i = 0; i < 12; ++i) acc0[i] = acc1[i] = 0.f;

    #pragma unroll 4
    for (int f = 0; f < 64; ++f) {
        float2 xv = *(const float2*)&xsT[f * 64 + rg * 2];
        const float* wr = &wc[f * 96 + cg * 12];
        float4 wA = *(const float4*)(wr);
        float4 wB = *(const float4*)(wr + 4);
        float4 wC = *(const float4*)(wr + 8);
        float wv_[12] = {wA.x, wA.y, wA.z, wA.w, wB.x, wB.y, wB.z, wB.w,
                         wC.x, wC.y, wC.z, wC.w};
        #pragma unroll
        for (int i = 0; i < 12; ++i) {
            acc0[i] += xv.x * wv_[i];
            acc1[i] += xv.y * wv_[i];
        }
    }
    __syncthreads();                   // wc reads done; reuse as output staging
    _Float16* os = (_Float16*)wc;      // q | k | v fragment regions

    // zero feature-group 3 (feats 24..31) of q and k regions (os aliases wc)
    if (t < 128) {
        int reg = t >> 6, rr = t & 63;
        *(f16x8*)&os[reg * 2048 + (rr >> 4) * 512 + (48 + (rr & 15)) * 8]
            = (f16x8){0, 0, 0, 0, 0, 0, 0, 0};
    }

    #pragma unroll
    for (int j = 0; j < 2; ++j) {
        int s = rg * 2 + j, st = s >> 4;
        const float* a = j ? acc1 : acc0;
        #pragma unroll
        for (int i = 0; i < 12; ++i) {
            int c = cg * 12 + i;
            if (c < 24) {
                os[st * 512 + ((c >> 3) * 16 + (s & 15)) * 8 + (c & 7)]
                    = (_Float16)(a[i] * L2E);
            } else if (c < 48) {
                int ck = c - 24;
                os[2048 + st * 512 + ((ck >> 3) * 16 + (s & 15)) * 8 + (ck & 7)]
                    = (_Float16)a[i];
            } else if (c < 80) {
                int vd = c - 48;
                os[4096 + st * 512 + (((s >> 2) & 3) * 16 + (vd & 15)) * 8
                   + (vd >> 4) * 4 + (s & 3)] = (_Float16)a[i];
            }
        }
    }
    __syncthreads();

    long blk = blockIdx.x;
    *(f16x8*)(qfp + blk * 2048 + t * 8) = *(const f16x8*)&os[t * 8];
    *(f16x8*)(kfp + blk * 2048 + t * 8) = *(const f16x8*)&os[2048 + t * 8];
    *(f16x8*)(vfp + blk * 2048 + t * 8) = *(const f16x8*)&os[4096 + t * 8];
}

// ---------------- Kernel B: partial column-softmax sums ----------------
// LDS-staged (C_r5-proven structure): 4 waves own 64 k each (4 hoisted
// K-frags); block shares a GLDS double-buffered q-stream (4 frags = 4 KB per
// round, 4 rounds of 256 q). One barrier per round.
__global__ __launch_bounds__(256) void stats_kernel(
    const _Float16* __restrict__ qf, const _Float16* __restrict__ kf,
    float* __restrict__ zpart)
{
    __shared__ __align__(16) _Float16 qtile[2][2048];  // 4 KB per buffer
    int w = blockIdx.x;
    int b = w >> 6, rest = w & 63;     // same-b blocks contiguous (L2/XCD)
    int kb = rest >> 3, qs = rest & 7;
    int t = threadIdx.x;
    int wv = t >> 6, l = t & 63, llo = l & 15, lhi = l >> 4;

    const _Float16* kfb = kf + ((long)b * 128 + kb * 16 + wv * 4) * 512 + l * 8;
    f16x8 af[4];
    #pragma unroll
    for (int kt = 0; kt < 4; ++kt) af[kt] = *(const f16x8*)(kfb + kt * 512);

    // wave wv stages frag (round*4 + wv); lane offset l*8 on the GLOBAL side
    const _Float16* qsrc = qf + ((long)b * 128 + qs * 16 + wv) * 512 + l * 8;
    f32x4 z[4] = {{0,0,0,0},{0,0,0,0},{0,0,0,0},{0,0,0,0}};

    GLDS16(qsrc, &qtile[0][wv * 512]);
    for (int rnd = 0; rnd < 4; ++rnd) {
        int cb = rnd & 1;
        __syncthreads();   // own stage drained at barrier -> qtile[cb] ready
        if (rnd < 3) GLDS16(qsrc + (rnd + 1) * 2048, &qtile[cb ^ 1][wv * 512]);
        #pragma unroll
        for (int fi = 0; fi < 4; ++fi) {
            f16x8 q0 = *(const f16x8*)&qtile[cb][fi * 512 + l * 8];
            #pragma unroll
            for (int kt = 0; kt < 4; ++kt) {
                f32x4 d = __builtin_amdgcn_mfma_f32_16x16x32_f16(af[kt], q0,
                            (f32x4){0.f, 0.f, 0.f, 0.f}, 0, 0, 0);
                #pragma unroll
                for (int r = 0; r < 4; ++r) z[kt][r] += __builtin_amdgcn_exp2f(d[r]);
            }
        }
    }
    #pragma unroll
    for (int m = 1; m < 16; m <<= 1)
        #pragma unroll
        for (int kt = 0; kt < 4; ++kt)
            #pragma unroll
            for (int r = 0; r < 4; ++r) z[kt][r] += __shfl_xor(z[kt][r], m, 64);
    if (llo == 0) {
        #pragma unroll
        for (int kt = 0; kt < 4; ++kt)
            *(f32x4*)(zpart + ((long)qs * 32 + b) * SS + kb * 256 + wv * 64
                      + kt * 16 + lhi * 4) = z[kt];
    }
}

// ---------------- Kernel B2: finalize wneg = -log2(sum of partials) --------
__global__ __launch_bounds__(256) void finalize_kernel(
    const float* __restrict__ zpart, float* __restrict__ wneg)
{
    int i = blockIdx.x * 256 + threadIdx.x;
    float s = 0.f;
    #pragma unroll
    for (int qs = 0; qs < 8; ++qs) s += zpart[(long)qs * 32 * SS + i];
    wneg[i] = -__builtin_amdgcn_logf(s);
}

// ---------------- Kernel C: attention + output projection ----------------
// r5-proven staged structure: 4 waves split q (16 rows each, private accs);
// shared double-buffered LDS K/V/w tiles (64 k) via global_load_lds; one
// barrier per tile. V now a single b128 per iter (r7 vf layout).
__global__ __launch_bounds__(256) void attn_out_kernel(
    const _Float16* __restrict__ qf, const _Float16* __restrict__ kf,
    const _Float16* __restrict__ vf, const float* __restrict__ wneg,
    const float* __restrict__ Wh, float* __restrict__ out)
{
    __shared__ __align__(16) _Float16 lds[2][4224];  // K 2048 | V 2048 | w 64 f32

    int w = blockIdx.x;
    int b = w >> 5, qblk = w & 31;     // same-b blocks contiguous
    int t = threadIdx.x;
    int wv = t >> 6, l = t & 63, llo = l & 15, lhi = l >> 4;
    int q0 = qblk * 64 + wv * 16;

    f16x8 qfr = *(const f16x8*)(qf + ((long)b * 128 + qblk * 4 + wv) * 512 + l * 8);

    f16x4 whlo[4], whhi[4];
    #pragma unroll
    for (int fb = 0; fb < 4; ++fb)
        #pragma unroll
        for (int j = 0; j < 4; ++j) {
            whlo[fb][j] = (_Float16)Wh[(4 * lhi + j) * 64 + fb * 16 + llo];
            whhi[fb][j] = (_Float16)Wh[(16 + 4 * lhi + j) * 64 + fb * 16 + llo];
        }

    const _Float16* kgb = kf + ((long)b * 128 + wv) * 512 + l * 8;   // + tile*2048
    const _Float16* vgb = vf + (long)b * 65536 + wv * 512 + l * 8;   // + tile*2048
    const float*    wgb = wneg + (long)b * SS + l;                   // + tile*64

    f32x4 acc0 = {0,0,0,0}, acc1 = {0,0,0,0};

    GLDS16(kgb, &lds[0][wv * 512]);
    GLDS16(vgb, &lds[0][2048 + wv * 512]);
    if (wv == 0) GLDS4(wgb, (float*)&lds[0][4096]);

    for (int tile = 0; tile < 32; ++tile) {
        int cb = tile & 1;
        __syncthreads();   // own stage drained at barrier -> lds[cb] ready
        if (tile < 31) {   // stage next tile; flight overlaps compute below
            GLDS16(kgb + (long)(tile + 1) * 2048, &lds[cb ^ 1][wv * 512]);
            GLDS16(vgb + (long)(tile + 1) * 2048, &lds[cb ^ 1][2048 + wv * 512]);
            if (wv == 0) GLDS4(wgb + (tile + 1) * 64, (float*)&lds[cb ^ 1][4096]);
        }
        const _Float16* Kb = &lds[cb][0];
        const _Float16* Vb = &lds[cb][2048];
        const float*    Wb = (const float*)&lds[cb][4096];
        #pragma unroll
        for (int t4 = 0; t4 < 4; ++t4) {
            f16x8 kfr = *(const f16x8*)(Kb + t4 * 512 + l * 8);
            float4 w4 = *(const float4*)(Wb + t4 * 16 + lhi * 4);
            f32x4 d = __builtin_amdgcn_mfma_f32_16x16x32_f16(kfr, qfr,
                        (f32x4){w4.x, w4.y, w4.z, w4.w}, 0, 0, 0);
            f16x4 pa;
            #pragma unroll
            for (int r = 0; r < 4; ++r) pa[r] = (_Float16)__builtin_amdgcn_exp2f(d[r]);
            f16x8 v01 = *(const f16x8*)(Vb + t4 * 512 + l * 8);
            f16x4 v0 = {v01[0], v01[1], v01[2], v01[3]};
            f16x4 v1 = {v01[4], v01[5], v01[6], v01[7]};
            acc0 = __builtin_amdgcn_mfma_f32_16x16x16f16(v0, pa, acc0, 0, 0, 0);
            acc1 = __builtin_amdgcn_mfma_f32_16x16x16f16(v1, pa, acc1, 0, 0, 0);
        }
    }

    // epilogue: O^T = Wh^T * h1^T via MFMA; accs are already B-fragments.
    f16x4 h0, h1;
    #pragma unroll
    for (int r = 0; r < 4; ++r) {
        h0[r] = (_Float16)acc0[r];
        h1[r] = (_Float16)acc1[r];
    }
    float* orow = out + ((long)b * SS + q0 + llo) * 64 + 4 * lhi;
    #pragma unroll
    for (int fb = 0; fb < 4; ++fb) {
        f32x4 o = __builtin_amdgcn_mfma_f32_16x16x16f16(whlo[fb], h0,
                    (f32x4){0.f, 0.f, 0.f, 0.f}, 0, 0, 0);
        o = __builtin_amdgcn_mfma_f32_16x16x16f16(whhi[fb], h1, o, 0, 0, 0);
        *(f32x4*)(orow + fb * 16) = o;
    }
}

extern "C" void kernel_launch(void* const* d_in, const int* in_sizes, int n_in,
                              void* d_out, int out_size, void* d_ws, size_t ws_size,
                              hipStream_t stream) {
    const float* x  = (const float*)d_in[0];
    const float* Wq = (const float*)d_in[1];
    const float* Wk = (const float*)d_in[2];
    const float* Wv = (const float*)d_in[3];
    const float* Wh = (const float*)d_in[4];
    float* out = (float*)d_out;

    char* ws = (char*)d_ws;
    _Float16* qf  = (_Float16*)(ws);                           // 4 MB
    _Float16* kf  = (_Float16*)(ws + (4l << 20));              // 4 MB
    _Float16* vf  = (_Float16*)(ws + (8l << 20));              // 4 MB
    float* wneg   = (float*)(ws + (12l << 20));                // 256 KB
    float* zpart  = (float*)(ws + (12l << 20) + (256l << 10)); // 2 MB

    qkv_kernel<<<1024, 256, 0, stream>>>(x, Wq, Wk, Wv, qf, kf, vf);
    stats_kernel<<<2048, 256, 0, stream>>>(qf, kf, zpart);
    finalize_kernel<<<256, 256, 0, stream>>>(zpart, wneg);
    attn_out_kernel<<<1024, 256, 0, stream>>>(qf, kf, vf, wneg, Wh, out);
}

// Round 12
// 72.988 us; speedup vs baseline: 1.1817x; 1.1817x over previous
//
#include <hip/hip_runtime.h>
#include <hip/hip_fp16.h>

#define SS 2048
#define L2E 1.44269504088896340736f

typedef _Float16 f16x4 __attribute__((ext_vector_type(4)));
typedef _Float16 f16x8 __attribute__((ext_vector_type(8)));
typedef float f32x4 __attribute__((ext_vector_type(4)));

#define GLDS16(g, l) __builtin_amdgcn_global_load_lds(                          \
    (const __attribute__((address_space(1))) void*)(g),                         \
    (__attribute__((address_space(3))) void*)(l), 16, 0, 0)
#define GLDS4(g, l) __builtin_amdgcn_global_load_lds(                           \
    (const __attribute__((address_space(1))) void*)(g),                         \
    (__attribute__((address_space(3))) void*)(l), 4, 0, 0)

// ---------------- Kernel A: QKV projection via MFMA ----------------
// Padded-96 weight cols: q 0..31 (24 real), k 32..63 (24 real), v 64..95.
// Per wave: one 16-row tile, 6 col-tiles x 2 K-steps = 12 MFMAs.
// Output scattered into the SAME fragment layouts as rounds 6-10:
//  qf/kf: [b][tile=s/16][ (feat/8)*16 + s%16 ][8]; q pre-scaled by log2e; fg3 zero.
//  vf: per 16k chunk: idx = (((s>>2)&3)*16 + (vd&15))*8 + (vd>>4)*4 + (s&3)
__global__ __launch_bounds__(256) void qkv_kernel(
    const float* __restrict__ x, const float* __restrict__ Wq,
    const float* __restrict__ Wk, const float* __restrict__ Wv,
    _Float16* __restrict__ qfp, _Float16* __restrict__ kfp,
    _Float16* __restrict__ vfp)
{
    __shared__ float wcs[64 * 96];                    // 24 KB raw weights [f][c96]
    __shared__ __align__(16) _Float16 wfb[12 * 512];  // 12 KB B-fragments

    int t = threadIdx.x;
    int wv = t >> 6, l = t & 63, llo = l & 15, lhi = l >> 4;

    // ---- stage raw weights (b128) + zero pad cols (disjoint addresses) ----
    for (int i = t; i < 384; i += 256) {
        float4 v = ((const float4*)Wq)[i];
        int f = (i * 4) / 24, c = (i * 4) % 24;
        *(float4*)&wcs[f * 96 + c] = v;
    }
    for (int i = t; i < 384; i += 256) {
        float4 v = ((const float4*)Wk)[i];
        int f = (i * 4) / 24, c = (i * 4) % 24;
        *(float4*)&wcs[f * 96 + 32 + c] = v;
    }
    for (int i = t; i < 512; i += 256) {
        float4 v = ((const float4*)Wv)[i];
        int f = i >> 3, c = (i * 4) & 31;
        *(float4*)&wcs[f * 96 + 64 + c] = v;
    }
    {   // zero pad cols 24..31 and 56..63
        int f = t >> 2, which = t & 3;
        int c = (which < 2) ? (24 + which * 4) : (56 + (which - 2) * 4);
        *(float4*)&wcs[f * 96 + c] = (float4){0.f, 0.f, 0.f, 0.f};
    }
    __syncthreads();

    // ---- build B-fragments: wfb[ct*2+kk][lane][8] ----
    #pragma unroll
    for (int p = 0; p < 3; ++p) {
        int sidx = t + p * 256;
        int fr = sidx >> 6, lane = sidx & 63;
        int ct = fr >> 1, kk = fr & 1;
        int lls = lane & 15, lhs = lane >> 4;
        f16x8 wfr;
        #pragma unroll
        for (int j = 0; j < 8; ++j)
            wfr[j] = (_Float16)wcs[(kk * 32 + lhs * 8 + j) * 96 + ct * 16 + lls];
        *(f16x8*)&wfb[fr * 512 + lane * 8] = wfr;
    }
    __syncthreads();

    _Float16* os = (_Float16*)wcs;   // q | k | v fragment staging (aliases wcs)

    // zero fg3 of q and k regions (pad features 24..31)
    if (t < 128) {
        int reg = t >> 6, rr = t & 63;
        *(f16x8*)&os[reg * 2048 + (rr >> 4) * 512 + (48 + (rr & 15)) * 8]
            = (f16x8){0, 0, 0, 0, 0, 0, 0, 0};
    }

    // ---- A-frags direct from global x (16 rows per wave) ----
    long rowbase = (long)blockIdx.x * 64;
    const float* xr = x + (rowbase + wv * 16 + llo) * 64 + lhi * 8;
    f16x8 a0, a1;
    {
        float4 u0 = *(const float4*)(xr);
        float4 u1 = *(const float4*)(xr + 4);
        float4 u2 = *(const float4*)(xr + 32);
        float4 u3 = *(const float4*)(xr + 36);
        a0[0] = (_Float16)u0.x; a0[1] = (_Float16)u0.y;
        a0[2] = (_Float16)u0.z; a0[3] = (_Float16)u0.w;
        a0[4] = (_Float16)u1.x; a0[5] = (_Float16)u1.y;
        a0[6] = (_Float16)u1.z; a0[7] = (_Float16)u1.w;
        a1[0] = (_Float16)u2.x; a1[1] = (_Float16)u2.y;
        a1[2] = (_Float16)u2.z; a1[3] = (_Float16)u2.w;
        a1[4] = (_Float16)u3.x; a1[5] = (_Float16)u3.y;
        a1[6] = (_Float16)u3.z; a1[7] = (_Float16)u3.w;
    }

    f32x4 d[6];
    #pragma unroll
    for (int ct = 0; ct < 6; ++ct) {
        f16x8 b0 = *(const f16x8*)&wfb[(ct * 2 + 0) * 512 + l * 8];
        f16x8 b1 = *(const f16x8*)&wfb[(ct * 2 + 1) * 512 + l * 8];
        d[ct] = __builtin_amdgcn_mfma_f32_16x16x32_f16(a0, b0,
                  (f32x4){0.f, 0.f, 0.f, 0.f}, 0, 0, 0);
        d[ct] = __builtin_amdgcn_mfma_f32_16x16x32_f16(a1, b1, d[ct], 0, 0, 0);
    }

    // ---- scatter D-tiles into fragment staging ----
    // lane holds out[s%16 = lhi*4+r][c = ct*16+llo]
    #pragma unroll
    for (int r = 0; r < 4; ++r) {
        int sl = lhi * 4 + r;
        os[wv * 512 + ((llo >> 3) * 16 + sl) * 8 + (llo & 7)]
            = (_Float16)(d[0][r] * L2E);
        if (llo < 8)
            os[wv * 512 + (32 + sl) * 8 + llo] = (_Float16)(d[1][r] * L2E);
        os[2048 + wv * 512 + ((llo >> 3) * 16 + sl) * 8 + (llo & 7)]
            = (_Float16)d[2][r];
        if (llo < 8)
            os[2048 + wv * 512 + (32 + sl) * 8 + llo] = (_Float16)d[3][r];
        os[4096 + wv * 512 + (lhi * 16 + llo) * 8 + r]     = (_Float16)d[4][r];
        os[4096 + wv * 512 + (lhi * 16 + llo) * 8 + 4 + r] = (_Float16)d[5][r];
    }
    __syncthreads();

    long blk = blockIdx.x;
    *(f16x8*)(qfp + blk * 2048 + t * 8) = *(const f16x8*)&os[t * 8];
    *(f16x8*)(kfp + blk * 2048 + t * 8) = *(const f16x8*)&os[2048 + t * 8];
    *(f16x8*)(vfp + blk * 2048 + t * 8) = *(const f16x8*)&os[4096 + t * 8];
}

// ---------------- Kernel B: partial column-softmax sums ----------------
// (byte-identical to round 10 — PASSING version)
__global__ __launch_bounds__(256) void stats_kernel(
    const _Float16* __restrict__ qf, const _Float16* __restrict__ kf,
    float* __restrict__ zpart)
{
    __shared__ __align__(16) _Float16 qtile[2][2048];  // 4 KB per buffer
    int w = blockIdx.x;
    int b = w >> 6, rest = w & 63;
    int kb = rest >> 3, qs = rest & 7;
    int t = threadIdx.x;
    int wv = t >> 6, l = t & 63, llo = l & 15, lhi = l >> 4;

    const _Float16* kfb = kf + ((long)b * 128 + kb * 16 + wv * 4) * 512 + l * 8;
    f16x8 af[4];
    #pragma unroll
    for (int kt = 0; kt < 4; ++kt) af[kt] = *(const f16x8*)(kfb + kt * 512);

    const _Float16* qsrc = qf + ((long)b * 128 + qs * 16 + wv) * 512 + l * 8;
    f32x4 z[4] = {{0,0,0,0},{0,0,0,0},{0,0,0,0},{0,0,0,0}};

    GLDS16(qsrc, &qtile[0][wv * 512]);
    for (int rnd = 0; rnd < 4; ++rnd) {
        int cb = rnd & 1;
        __syncthreads();
        if (rnd < 3) GLDS16(qsrc + (rnd + 1) * 2048, &qtile[cb ^ 1][wv * 512]);
        #pragma unroll
        for (int fi = 0; fi < 4; ++fi) {
            f16x8 q0 = *(const f16x8*)&qtile[cb][fi * 512 + l * 8];
            #pragma unroll
            for (int kt = 0; kt < 4; ++kt) {
                f32x4 d = __builtin_amdgcn_mfma_f32_16x16x32_f16(af[kt], q0,
                            (f32x4){0.f, 0.f, 0.f, 0.f}, 0, 0, 0);
                #pragma unroll
                for (int r = 0; r < 4; ++r) z[kt][r] += __builtin_amdgcn_exp2f(d[r]);
            }
        }
    }
    #pragma unroll
    for (int m = 1; m < 16; m <<= 1)
        #pragma unroll
        for (int kt = 0; kt < 4; ++kt)
            #pragma unroll
            for (int r = 0; r < 4; ++r) z[kt][r] += __shfl_xor(z[kt][r], m, 64);
    if (llo == 0) {
        #pragma unroll
        for (int kt = 0; kt < 4; ++kt)
            *(f32x4*)(zpart + ((long)qs * 32 + b) * SS + kb * 256 + wv * 64
                      + kt * 16 + lhi * 4) = z[kt];
    }
}

// ---------------- Kernel B2: finalize wneg = -log2(sum of partials) --------
__global__ __launch_bounds__(256) void finalize_kernel(
    const float* __restrict__ zpart, float* __restrict__ wneg)
{
    int i = blockIdx.x * 256 + threadIdx.x;
    float s = 0.f;
    #pragma unroll
    for (int qs = 0; qs < 8; ++qs) s += zpart[(long)qs * 32 * SS + i];
    wneg[i] = -__builtin_amdgcn_logf(s);
}

// ---------------- Kernel C: attention + output projection ----------------
// (byte-identical to round 10 — PASSING version)
__global__ __launch_bounds__(256) void attn_out_kernel(
    const _Float16* __restrict__ qf, const _Float16* __restrict__ kf,
    const _Float16* __restrict__ vf, const float* __restrict__ wneg,
    const float* __restrict__ Wh, float* __restrict__ out)
{
    __shared__ __align__(16) _Float16 lds[2][4224];  // K 2048 | V 2048 | w 64 f32

    int w = blockIdx.x;
    int b = w >> 5, qblk = w & 31;
    int t = threadIdx.x;
    int wv = t >> 6, l = t & 63, llo = l & 15, lhi = l >> 4;
    int q0 = qblk * 64 + wv * 16;

    f16x8 qfr = *(const f16x8*)(qf + ((long)b * 128 + qblk * 4 + wv) * 512 + l * 8);

    f16x4 whlo[4], whhi[4];
    #pragma unroll
    for (int fb = 0; fb < 4; ++fb)
        #pragma unroll
        for (int j = 0; j < 4; ++j) {
            whlo[fb][j] = (_Float16)Wh[(4 * lhi + j) * 64 + fb * 16 + llo];
            whhi[fb][j] = (_Float16)Wh[(16 + 4 * lhi + j) * 64 + fb * 16 + llo];
        }

    const _Float16* kgb = kf + ((long)b * 128 + wv) * 512 + l * 8;   // + tile*2048
    const _Float16* vgb = vf + (long)b * 65536 + wv * 512 + l * 8;   // + tile*2048
    const float*    wgb = wneg + (long)b * SS + l;                   // + tile*64

    f32x4 acc0 = {0,0,0,0}, acc1 = {0,0,0,0};

    GLDS16(kgb, &lds[0][wv * 512]);
    GLDS16(vgb, &lds[0][2048 + wv * 512]);
    if (wv == 0) GLDS4(wgb, (float*)&lds[0][4096]);

    for (int tile = 0; tile < 32; ++tile) {
        int cb = tile & 1;
        __syncthreads();
        if (tile < 31) {
            GLDS16(kgb + (long)(tile + 1) * 2048, &lds[cb ^ 1][wv * 512]);
            GLDS16(vgb + (long)(tile + 1) * 2048, &lds[cb ^ 1][2048 + wv * 512]);
            if (wv == 0) GLDS4(wgb + (tile + 1) * 64, (float*)&lds[cb ^ 1][4096]);
        }
        const _Float16* Kb = &lds[cb][0];
        const _Float16* Vb = &lds[cb][2048];
        const float*    Wb = (const float*)&lds[cb][4096];
        #pragma unroll
        for (int t4 = 0; t4 < 4; ++t4) {
            f16x8 kfr = *(const f16x8*)(Kb + t4 * 512 + l * 8);
            float4 w4 = *(const float4*)(Wb + t4 * 16 + lhi * 4);
            f32x4 d = __builtin_amdgcn_mfma_f32_16x16x32_f16(kfr, qfr,
                        (f32x4){w4.x, w4.y, w4.z, w4.w}, 0, 0, 0);
            f16x4 pa;
            #pragma unroll
            for (int r = 0; r < 4; ++r) pa[r] = (_Float16)__builtin_amdgcn_exp2f(d[r]);
            f16x8 v01 = *(const f16x8*)(Vb + t4 * 512 + l * 8);
            f16x4 v0 = {v01[0], v01[1], v01[2], v01[3]};
            f16x4 v1 = {v01[4], v01[5], v01[6], v01[7]};
            acc0 = __builtin_amdgcn_mfma_f32_16x16x16f16(v0, pa, acc0, 0, 0, 0);
            acc1 = __builtin_amdgcn_mfma_f32_16x16x16f16(v1, pa, acc1, 0, 0, 0);
        }
    }

    f16x4 h0, h1;
    #pragma unroll
    for (int r = 0; r < 4; ++r) {
        h0[r] = (_Float16)acc0[r];
        h1[r] = (_Float16)acc1[r];
    }
    float* orow = out + ((long)b * SS + q0 + llo) * 64 + 4 * lhi;
    #pragma unroll
    for (int fb = 0; fb < 4; ++fb) {
        f32x4 o = __builtin_amdgcn_mfma_f32_16x16x16f16(whlo[fb], h0,
                    (f32x4){0.f, 0.f, 0.f, 0.f}, 0, 0, 0);
        o = __builtin_amdgcn_mfma_f32_16x16x16f16(whhi[fb], h1, o, 0, 0, 0);
        *(f32x4*)(orow + fb * 16) = o;
    }
}

extern "C" void kernel_launch(void* const* d_in, const int* in_sizes, int n_in,
                              void* d_out, int out_size, void* d_ws, size_t ws_size,
                              hipStream_t stream) {
    const float* x  = (const float*)d_in[0];
    const float* Wq = (const float*)d_in[1];
    const float* Wk = (const float*)d_in[2];
    const float* Wv = (const float*)d_in[3];
    const float* Wh = (const float*)d_in[4];
    float* out = (float*)d_out;

    char* ws = (char*)d_ws;
    _Float16* qf  = (_Float16*)(ws);                           // 4 MB
    _Float16* kf  = (_Float16*)(ws + (4l << 20));              // 4 MB
    _Float16* vf  = (_Float16*)(ws + (8l << 20));              // 4 MB
    float* wneg   = (float*)(ws + (12l << 20));                // 256 KB
    float* zpart  = (float*)(ws + (12l << 20) + (256l << 10)); // 2 MB

    qkv_kernel<<<1024, 256, 0, stream>>>(x, Wq, Wk, Wv, qf, kf, vf);
    stats_kernel<<<2048, 256, 0, stream>>>(qf, kf, zpart);
    finalize_kernel<<<256, 256, 0, stream>>>(zpart, wneg);
    attn_out_kernel<<<1024, 256, 0, stream>>>(qf, kf, vf, wneg, Wh, out);
}